// Round 1
// baseline (565.009 us; speedup 1.0000x reference)
//
#include <hip/hip_runtime.h>

// Problem dims (fixed by setup_inputs)
#define BN 16      // batch
#define FD 256     // features
#define SH 64      // small h
#define SW 64      // small w
#define BH 512     // big H
#define BW 512     // big W
#define KN 21      // classes
#define SP (SH*SW)   // 4096 small pixels
#define BP (BH*BW)   // 262144 big pixels

#define SEG_BLOCKS 256                 // 65536 threads, 1 px each
#define DOWNX_BLOCKS (BN*3*BH/4)       // 6144: one block = (bc, 4 Y rows)

typedef float f32x4 __attribute__((ext_vector_type(4)));

// ---------------------------------------------------------------------------
// Adjoint bilinear (align_corners=True) weight in f32.
// Exactness: X*63/511 lands on an integer only at X = 73*m (t = 9m exact in
// f32); elsewhere min distance to an integer is 1/511 ~ 2e-3 >> f32 error
// ~4e-6, so floor() never crosses. Residual weight error ~3e-8 << tolerance.
__device__ __forceinline__ float adj_w(int big, int small) {
    float t = (float)big * (63.0f / 511.0f);
    int i0 = (int)t;
    float fr = t - (float)i0;
    int i1 = i0 + 1; if (i1 > 63) i1 = 63;
    float w = 0.0f;
    if (i0 == small) w += 1.0f - fr;
    if (i1 == small) w += fr;
    return w;
}

__device__ __forceinline__ void adj_range(int small, int& lo, int& hi) {
    lo = (int)floorf((small - 1) * (511.0f / 63.0f)); if (lo < 0) lo = 0;
    hi = (int)ceilf((small + 1) * (511.0f / 63.0f));  if (hi > 511) hi = 511;
}

// ---------------------------------------------------------------------------
// seg: 1x1 conv + softmax, ONE pixel per thread (4x shorter serial FMA chain
// than the old float4 version; same total VALU work, 4x the waves).
__device__ __forceinline__ void seg_body(int blk, int tid,
                                         const float* __restrict__ fm,
                                         const float* __restrict__ cw,
                                         const float* __restrict__ cb,
                                         float* __restrict__ seg) {
    int gid = blk * 256 + tid;          // 0..65535
    int b   = gid >> 12;                // 4096 px per batch
    int p   = gid & 4095;
    const float* fmb = fm + (size_t)b * FD * SP + p;

    float acc[KN];
#pragma unroll
    for (int k = 0; k < KN; ++k) acc[k] = 0.0f;

#pragma unroll 4
    for (int f = 0; f < FD; ++f) {
        float v = fmb[(size_t)f * SP];   // 256B coalesced per wave
#pragma unroll
        for (int k = 0; k < KN; ++k)
            acc[k] = fmaf(v, cw[k * FD + f], acc[k]);   // cw uniform -> s_load
    }

    float mx = -1e30f;
#pragma unroll
    for (int k = 0; k < KN; ++k) { acc[k] += cb[k]; mx = fmaxf(mx, acc[k]); }
    float s = 0.0f;
#pragma unroll
    for (int k = 0; k < KN; ++k) { acc[k] = expf(acc[k] - mx); s += acc[k]; }
    float inv = 1.0f / s;

    float* segb = seg + (size_t)b * KN * SP + p;
#pragma unroll
    for (int k = 0; k < KN; ++k) segb[(size_t)k * SP] = acc[k] * inv;
}

// downx: tmpA[bc, Y, s] = sum_X W[X,s] * x[bc, Y, X]
// LDS-staged: block loads 4 full rows (8 KB) with coalesced float4 loads,
// then gathers from LDS (old version: per-lane stride-8 global gathers).
__device__ __forceinline__ void downx_body(int blk, int tid,
                                           const float* __restrict__ x,
                                           float* __restrict__ tmpA,
                                           float (*rows)[BW]) {
    int bc = blk >> 7;                  // 0..47
    int Y0 = (blk & 127) << 2;          // 4 Y rows per block
    const f32x4* src = (const f32x4*)(x + ((size_t)bc * BH + Y0) * BW);
    f32x4* dst = (f32x4*)&rows[0][0];
    dst[tid]       = src[tid];          // 2048 floats = 512 float4, 2/thread
    dst[tid + 256] = src[tid + 256];
    __syncthreads();

    int s  = tid & 63;
    int yl = tid >> 6;
    int lo, hi; adj_range(s, lo, hi);
    float acc = 0.0f;
    for (int X = lo; X <= hi; ++X) acc = fmaf(adj_w(X, s), rows[yl][X], acc);
    tmpA[((size_t)bc * BH + Y0 + yl) * SW + s] = acc;   // 256B coalesced
}

// Phase 1: seg (blocks [0,256)) runs concurrently with downx (blocks [256,6400))
__global__ __launch_bounds__(256) void k_phase1(const float* __restrict__ fm,
                                                const float* __restrict__ cw,
                                                const float* __restrict__ cb,
                                                const float* __restrict__ x,
                                                float* __restrict__ seg,
                                                float* __restrict__ tmpA) {
    __shared__ float rows[4][BW];       // 8 KB (unused by seg blocks)
    if (blockIdx.x < SEG_BLOCKS) seg_body(blockIdx.x, threadIdx.x, fm, cw, cb, seg);
    else                         downx_body(blockIdx.x - SEG_BLOCKS, threadIdx.x, x, tmpA, rows);
}

// ---------------------------------------------------------------------------
// Fused downy + q: one block per (b,c) owns q[b,:,c] — no xd buffer, no
// atomics, one launch instead of two.
//   xd[bc,r,s] = sum_Y W[Y,r] * tmpA[bc,Y,s]   (kept in registers)
//   q[b,k,c]   = (1/BP) * sum_{r,s} seg[b,k,r*64+s] * xd[bc,r,s]
__global__ __launch_bounds__(256) void k_downyq(const float* __restrict__ tmpA,
                                                const float* __restrict__ seg,
                                                float* __restrict__ q) {
    int bc = blockIdx.x;                // 0..47
    int b  = bc / 3, c = bc - b * 3;
    const float* base = tmpA + (size_t)bc * BH * SW;
    const float* segb = seg + (size_t)b * KN * SP;

    float qk[KN];
#pragma unroll
    for (int k = 0; k < KN; ++k) qk[k] = 0.0f;

    for (int i = 0; i < SP / 256; ++i) {        // 16 iterations
        int p = i * 256 + threadIdx.x;
        int r = p >> 6, s = p & 63;             // whole wave shares r -> uniform loop
        int lo, hi; adj_range(r, lo, hi);
        float xv = 0.0f;
        for (int Y = lo; Y <= hi; ++Y)
            xv = fmaf(adj_w(Y, r), base[(size_t)Y * SW + s], xv);   // 256B coalesced
#pragma unroll
        for (int k = 0; k < KN; ++k)
            qk[k] = fmaf(segb[(size_t)k * SP + p], xv, qk[k]);      // 1KB coalesced
    }

    // wave shfl-reduce, then 4 partials per k through LDS (1 barrier total)
    __shared__ float red[4][KN];
    int lane = threadIdx.x & 63, w = threadIdx.x >> 6;
#pragma unroll
    for (int k = 0; k < KN; ++k) {
        float v = qk[k];
        for (int off = 32; off > 0; off >>= 1) v += __shfl_down(v, off, 64);
        if (lane == 0) red[w][k] = v;
    }
    __syncthreads();
    if (threadIdx.x < KN) {
        float v = red[0][threadIdx.x] + red[1][threadIdx.x]
                + red[2][threadIdx.x] + red[3][threadIdx.x];
        q[((size_t)b * KN + threadIdx.x) * 3 + c] = v * (1.0f / (float)BP);
    }
}

// ---------------------------------------------------------------------------
// attn[b,k,p] = sum_c x[b,c,p] * q[b,k,c]; float4, REGULAR stores this round
// (A/B vs nontemporal: fill kernel + copy ubench both hit ~6.3-6.4 TB/s with
// regular stores; if the nt MTYPE path was throttling the 352 MB stream this
// is the whole remaining gap).
__global__ __launch_bounds__(256) void k_attn(const float* __restrict__ x,
                                              const float* __restrict__ q,
                                              float* __restrict__ out) {
    int b   = blockIdx.x >> 8;
    int blk = blockIdx.x & 255;
    int p4  = blk * 256 + threadIdx.x;

    const f32x4* xb = (const f32x4*)(x + (size_t)b * 3 * BP);
    f32x4 x0 = xb[p4];
    f32x4 x1 = xb[BP / 4 + p4];
    f32x4 x2 = xb[2 * (BP / 4) + p4];

    __shared__ float qs[KN * 3];
    if (threadIdx.x < KN * 3) qs[threadIdx.x] = q[(size_t)b * KN * 3 + threadIdx.x];
    __syncthreads();

    f32x4* ob = (f32x4*)(out + (size_t)b * KN * BP) + p4;
#pragma unroll
    for (int k = 0; k < KN; ++k) {
        float q0 = qs[k * 3], q1 = qs[k * 3 + 1], q2 = qs[k * 3 + 2];
        f32x4 r = x0 * q0 + x1 * q1 + x2 * q2;
        ob[(size_t)k * (BP / 4)] = r;
    }
}

// ---------------------------------------------------------------------------
extern "C" void kernel_launch(void* const* d_in, const int* in_sizes, int n_in,
                              void* d_out, int out_size, void* d_ws, size_t ws_size,
                              hipStream_t stream) {
    const float* fm = (const float*)d_in[0];   // [16,256,64,64]
    const float* x  = (const float*)d_in[1];   // [16,3,512,512]
    const float* cw = (const float*)d_in[2];   // [21,256]
    const float* cb = (const float*)d_in[3];   // [21]
    float* out = (float*)d_out;                // [16,21,512,512]

    // workspace layout (floats): seg | tmpA | q  (~11.8 MB total)
    float* seg  = (float*)d_ws;                       // 16*21*4096
    float* tmpA = seg  + (size_t)BN * KN * SP;        // 16*3*512*64
    float* q    = tmpA + (size_t)BN * 3 * BH * SW;    // 16*21*3

    k_phase1<<<SEG_BLOCKS + DOWNX_BLOCKS, 256, 0, stream>>>(fm, cw, cb, x, seg, tmpA);
    k_downyq<<<BN * 3,                    256, 0, stream>>>(tmpA, seg, q);
    k_attn  <<<BN * (BP / 1024),          256, 0, stream>>>(x, q, out);
}

// Round 2
// 511.187 us; speedup vs baseline: 1.1053x; 1.1053x over previous
//
#include <hip/hip_runtime.h>

// Problem dims (fixed by setup_inputs)
#define BN 16      // batch
#define FD 256     // features
#define SH 64      // small h
#define SW 64      // small w
#define BH 512     // big H
#define BW 512     // big W
#define KN 21      // classes
#define SP (SH*SW)   // 4096 small pixels
#define BP (BH*BW)   // 262144 big pixels

#define SEG_BLOCKS 64                      // 16384 threads, 4 px each
#define DOWNX_BLOCKS (BN*3*BH*SW/256)      // 6144

typedef float f32x4 __attribute__((ext_vector_type(4)));

// ---------------------------------------------------------------------------
// SINGLE CHANGE vs round 0: all intermediates live in __device__ globals
// (guaranteed VRAM) instead of d_ws. Tests the hypothesis that d_ws is not
// plain device memory (the only hypothesis that closes the ~400 µs gap
// between roofline (~110 µs) and measured (509 µs)).
__device__ float g_seg [(size_t)BN * KN * SP];     // 5.25 MiB
__device__ float g_tmpA[(size_t)BN * 3 * BH * SW]; // 6 MiB
__device__ float g_xd  [(size_t)BN * 3 * SP];      // 3 MiB
__device__ float g_q   [(size_t)BN * KN * 3];      // 4 KiB

// ---------------------------------------------------------------------------
// Adjoint bilinear (align_corners=True) weight: contribution of big index
// `big` onto small index `small`. scale = 63/511. f64 for exact floor edges.
__device__ __forceinline__ float adj_w(int big, int small) {
    double t = (double)big * (63.0 / 511.0);
    int i0 = (int)t;
    double fr = t - (double)i0;
    int i1 = i0 + 1; if (i1 > 63) i1 = 63;
    float w = 0.0f;
    if (i0 == small) w += (float)(1.0 - fr);
    if (i1 == small) w += (float)fr;
    return w;
}

__device__ __forceinline__ void adj_range(int small, int& lo, int& hi) {
    lo = (int)floorf((small - 1) * (511.0f / 63.0f)); if (lo < 0) lo = 0;
    hi = (int)ceilf((small + 1) * (511.0f / 63.0f));  if (hi > 511) hi = 511;
}

// ---------------------------------------------------------------------------
// seg: 1x1 conv + softmax, 4 pixels (one float4) per thread
__device__ __forceinline__ void seg_body(int blk, int tid,
                                         const float* __restrict__ fm,
                                         const float* __restrict__ cw,
                                         const float* __restrict__ cb) {
    int gid = blk * 256 + tid;          // 0..16383
    int b   = gid >> 10;                // 1024 float4-groups per batch
    int p4  = gid & 1023;
    const f32x4* fmb = (const f32x4*)(fm + (size_t)b * FD * SP) + p4;

    f32x4 acc[KN];
#pragma unroll
    for (int k = 0; k < KN; ++k) acc[k] = (f32x4)0.0f;

#pragma unroll 2
    for (int f = 0; f < FD; ++f) {
        f32x4 v = fmb[f * (SP / 4)];
#pragma unroll
        for (int k = 0; k < KN; ++k)
            acc[k] += v * cw[k * FD + f];
    }

    f32x4 mx = (f32x4)(-1e30f);
#pragma unroll
    for (int k = 0; k < KN; ++k) {
        acc[k] += cb[k];
        mx.x = fmaxf(mx.x, acc[k].x); mx.y = fmaxf(mx.y, acc[k].y);
        mx.z = fmaxf(mx.z, acc[k].z); mx.w = fmaxf(mx.w, acc[k].w);
    }
    f32x4 s = (f32x4)0.0f;
#pragma unroll
    for (int k = 0; k < KN; ++k) {
        acc[k].x = expf(acc[k].x - mx.x); acc[k].y = expf(acc[k].y - mx.y);
        acc[k].z = expf(acc[k].z - mx.z); acc[k].w = expf(acc[k].w - mx.w);
        s += acc[k];
    }
    f32x4 inv;
    inv.x = 1.0f / s.x; inv.y = 1.0f / s.y; inv.z = 1.0f / s.z; inv.w = 1.0f / s.w;

    f32x4* segb = (f32x4*)(g_seg + (size_t)b * KN * SP) + p4;
#pragma unroll
    for (int k = 0; k < KN; ++k) segb[k * (SP / 4)] = acc[k] * inv;
}

// downx: g_tmpA[bc, Y, s] = sum_X W[X,s] * x[bc, Y, X]
__device__ __forceinline__ void downx_body(int blk, int tid,
                                           const float* __restrict__ x) {
    int gid = blk * 256 + tid;       // ((bc)*BH + Y)*SW + s
    int s  = gid & 63;
    int Y  = (gid >> 6) & 511;
    int bc = gid >> 15;              // 0..47
    const float* row = x + ((size_t)bc * BH + Y) * BW;
    int lo, hi; adj_range(s, lo, hi);
    float acc = 0.0f;
    for (int X = lo; X <= hi; ++X) acc = fmaf(adj_w(X, s), row[X], acc);
    g_tmpA[gid] = acc;
}

// Phase 1: seg (blocks [0,64)) runs concurrently with downx (blocks [64,6208))
__global__ __launch_bounds__(256) void k_phase1(const float* __restrict__ fm,
                                                const float* __restrict__ cw,
                                                const float* __restrict__ cb,
                                                const float* __restrict__ x) {
    if (blockIdx.x < SEG_BLOCKS) seg_body(blockIdx.x, threadIdx.x, fm, cw, cb);
    else                         downx_body(blockIdx.x - SEG_BLOCKS, threadIdx.x, x);
}

// ---------------------------------------------------------------------------
// downy: g_xd[bc, r, s] = sum_Y W[Y,r] * g_tmpA[bc, Y, s]
__global__ __launch_bounds__(256) void k_downy() {
    int gid = blockIdx.x * 256 + threadIdx.x;   // ((bc)*SH + r)*SW + s
    int s  = gid & 63;
    int r  = (gid >> 6) & 63;
    int bc = gid >> 12;                          // 0..47
    const float* base = g_tmpA + (size_t)bc * BH * SW + s;
    int lo, hi; adj_range(r, lo, hi);
    float acc = 0.0f;
    for (int Y = lo; Y <= hi; ++Y) acc = fmaf(adj_w(Y, r), base[(size_t)Y * SW], acc);
    g_xd[gid] = acc;
}

// ---------------------------------------------------------------------------
// q[b,k,c] = (1/BP) * sum_p seg[b,k,p] * xd[b,c,p]; one block per (b,k)
__global__ __launch_bounds__(256) void k_q() {
    int b = blockIdx.x / KN, k = blockIdx.x % KN;
    const float* sg = g_seg + ((size_t)b * KN + k) * SP;
    const float* xb = g_xd + (size_t)b * 3 * SP;
    float a0 = 0.f, a1 = 0.f, a2 = 0.f;
    for (int p = threadIdx.x; p < SP; p += 256) {
        float sv = sg[p];
        a0 = fmaf(sv, xb[p], a0);
        a1 = fmaf(sv, xb[SP + p], a1);
        a2 = fmaf(sv, xb[2 * SP + p], a2);
    }
    __shared__ float red[3][256];
    red[0][threadIdx.x] = a0; red[1][threadIdx.x] = a1; red[2][threadIdx.x] = a2;
    __syncthreads();
    for (int off = 128; off > 0; off >>= 1) {
        if (threadIdx.x < (unsigned)off) {
            red[0][threadIdx.x] += red[0][threadIdx.x + off];
            red[1][threadIdx.x] += red[1][threadIdx.x + off];
            red[2][threadIdx.x] += red[2][threadIdx.x + off];
        }
        __syncthreads();
    }
    if (threadIdx.x == 0) {
        const float scale = 1.0f / (float)BP;
        float* qo = g_q + ((size_t)b * KN + k) * 3;
        qo[0] = red[0][0] * scale;
        qo[1] = red[1][0] * scale;
        qo[2] = red[2][0] * scale;
    }
}

// ---------------------------------------------------------------------------
// attn[b,k,p] = sum_c x[b,c,p] * q[b,k,c]; float4, nontemporal stores
__global__ __launch_bounds__(256) void k_attn(const float* __restrict__ x,
                                              float* __restrict__ out) {
    int b   = blockIdx.x >> 8;
    int blk = blockIdx.x & 255;
    int p4  = blk * 256 + threadIdx.x;

    const f32x4* xb = (const f32x4*)(x + (size_t)b * 3 * BP);
    f32x4 x0 = xb[p4];
    f32x4 x1 = xb[BP / 4 + p4];
    f32x4 x2 = xb[2 * (BP / 4) + p4];

    __shared__ float qs[KN * 3];
    if (threadIdx.x < KN * 3) qs[threadIdx.x] = g_q[(size_t)b * KN * 3 + threadIdx.x];
    __syncthreads();

    f32x4* ob = (f32x4*)(out + (size_t)b * KN * BP) + p4;
#pragma unroll
    for (int k = 0; k < KN; ++k) {
        float q0 = qs[k * 3], q1 = qs[k * 3 + 1], q2 = qs[k * 3 + 2];
        f32x4 r = x0 * q0 + x1 * q1 + x2 * q2;
        __builtin_nontemporal_store(r, ob + (size_t)k * (BP / 4));
    }
}

// ---------------------------------------------------------------------------
extern "C" void kernel_launch(void* const* d_in, const int* in_sizes, int n_in,
                              void* d_out, int out_size, void* d_ws, size_t ws_size,
                              hipStream_t stream) {
    const float* fm = (const float*)d_in[0];   // [16,256,64,64]
    const float* x  = (const float*)d_in[1];   // [16,3,512,512]
    const float* cw = (const float*)d_in[2];   // [21,256]
    const float* cb = (const float*)d_in[3];   // [21]
    float* out = (float*)d_out;                // [16,21,512,512]

    k_phase1<<<SEG_BLOCKS + DOWNX_BLOCKS, 256, 0, stream>>>(fm, cw, cb, x);
    k_downy <<<BN * 3 * SP / 256,         256, 0, stream>>>();
    k_q     <<<BN * KN,                   256, 0, stream>>>();
    k_attn  <<<BN * (BP / 1024),          256, 0, stream>>>(x, out);
}

// Round 3
// 480.047 us; speedup vs baseline: 1.1770x; 1.0649x over previous
//
#include <hip/hip_runtime.h>

// Problem dims (fixed by setup_inputs)
#define BN 16      // batch
#define FD 256     // features
#define SH 64      // small h
#define SW 64      // small w
#define BH 512     // big H
#define BW 512     // big W
#define KN 21      // classes
#define SP (SH*SW)   // 4096 small pixels
#define BP (BH*BW)   // 262144 big pixels

#define SEG_BLOCKS 256                     // 65536 threads, 1 px each (was 64 blk / 4 px)
#define DOWNX_BLOCKS (BN*3*BH*SW/256)      // 6144
#define QSPLIT 4                           // k_q parallelism: 4 blocks per (b,k)

typedef float f32x4 __attribute__((ext_vector_type(4)));

// ---------------------------------------------------------------------------
// Adjoint bilinear (align_corners=True) weight: contribution of big index
// `big` onto small index `small`. scale = 63/511. f64 for exact floor edges.
__device__ __forceinline__ float adj_w(int big, int small) {
    double t = (double)big * (63.0 / 511.0);
    int i0 = (int)t;
    double fr = t - (double)i0;
    int i1 = i0 + 1; if (i1 > 63) i1 = 63;
    float w = 0.0f;
    if (i0 == small) w += (float)(1.0 - fr);
    if (i1 == small) w += (float)fr;
    return w;
}

__device__ __forceinline__ void adj_range(int small, int& lo, int& hi) {
    lo = (int)floorf((small - 1) * (511.0f / 63.0f)); if (lo < 0) lo = 0;
    hi = (int)ceilf((small + 1) * (511.0f / 63.0f));  if (hi > 511) hi = 511;
}

// ---------------------------------------------------------------------------
// seg: 1x1 conv + softmax, ONE pixel per thread.
// CHANGE vs r0: 4 px/thread -> 1 px/thread. Same total FMA work, but
// 256 waves (1/CU, 1 of 4 SIMDs busy) -> 1024 waves (4/CU, all SIMDs busy);
// per-lane serial chain 21504 v_fma -> 5376 v_fma.
__device__ __forceinline__ void seg_body(int blk, int tid,
                                         const float* __restrict__ fm,
                                         const float* __restrict__ cw,
                                         const float* __restrict__ cb,
                                         float* __restrict__ seg) {
    int gid = blk * 256 + tid;          // 0..65535
    int b   = gid >> 12;                // 4096 px per batch
    int p   = gid & 4095;
    const float* fmb = fm + (size_t)b * FD * SP + p;

    float acc[KN];
#pragma unroll
    for (int k = 0; k < KN; ++k) acc[k] = 0.0f;

#pragma unroll 4
    for (int f = 0; f < FD; ++f) {
        float v = fmb[(size_t)f * SP];   // 256B coalesced per wave
#pragma unroll
        for (int k = 0; k < KN; ++k)
            acc[k] = fmaf(v, cw[k * FD + f], acc[k]);   // cw uniform -> s_load
    }

    float mx = -1e30f;
#pragma unroll
    for (int k = 0; k < KN; ++k) { acc[k] += cb[k]; mx = fmaxf(mx, acc[k]); }
    float s = 0.0f;
#pragma unroll
    for (int k = 0; k < KN; ++k) { acc[k] = expf(acc[k] - mx); s += acc[k]; }
    float inv = 1.0f / s;

    float* segb = seg + (size_t)b * KN * SP + p;
#pragma unroll
    for (int k = 0; k < KN; ++k) segb[(size_t)k * SP] = acc[k] * inv;   // 256B coalesced
}

// downx: tmpA[bc, Y, s] = sum_X W[X,s] * x[bc, Y, X]   (identical to r0)
__device__ __forceinline__ void downx_body(int blk, int tid,
                                           const float* __restrict__ x,
                                           float* __restrict__ tmpA) {
    int gid = blk * 256 + tid;       // ((bc)*BH + Y)*SW + s
    int s  = gid & 63;
    int Y  = (gid >> 6) & 511;
    int bc = gid >> 15;              // 0..47
    const float* row = x + ((size_t)bc * BH + Y) * BW;
    int lo, hi; adj_range(s, lo, hi);
    float acc = 0.0f;
    for (int X = lo; X <= hi; ++X) acc = fmaf(adj_w(X, s), row[X], acc);
    tmpA[gid] = acc;
}

// Phase 1: seg (blocks [0,256)) runs concurrently with downx (blocks [256,6400))
__global__ __launch_bounds__(256) void k_phase1(const float* __restrict__ fm,
                                                const float* __restrict__ cw,
                                                const float* __restrict__ cb,
                                                const float* __restrict__ x,
                                                float* __restrict__ seg,
                                                float* __restrict__ tmpA) {
    if (blockIdx.x < SEG_BLOCKS) seg_body(blockIdx.x, threadIdx.x, fm, cw, cb, seg);
    else                         downx_body(blockIdx.x - SEG_BLOCKS, threadIdx.x, x, tmpA);
}

// ---------------------------------------------------------------------------
// downy: xd[bc, r, s] = sum_Y W[Y,r] * tmpA[bc, Y, s]   (identical to r0,
// plus: first 4 blocks zero q — ws is poisoned and k_q now atomically
// accumulates into q; the kernel boundary orders the zeroing before k_q).
__global__ __launch_bounds__(256) void k_downy(const float* __restrict__ tmpA,
                                               float* __restrict__ xd,
                                               float* __restrict__ q) {
    if (blockIdx.x < 4) {
        int i = blockIdx.x * 256 + threadIdx.x;
        if (i < BN * KN * 3) q[i] = 0.0f;
    }
    int gid = blockIdx.x * 256 + threadIdx.x;   // ((bc)*SH + r)*SW + s
    int s  = gid & 63;
    int r  = (gid >> 6) & 63;
    int bc = gid >> 12;                          // 0..47
    const float* base = tmpA + (size_t)bc * BH * SW + s;
    int lo, hi; adj_range(r, lo, hi);
    float acc = 0.0f;
    for (int Y = lo; Y <= hi; ++Y) acc = fmaf(adj_w(Y, r), base[(size_t)Y * SW], acc);
    xd[gid] = acc;
}

// ---------------------------------------------------------------------------
// q[b,k,c] = (1/BP) * sum_p seg[b,k,p] * xd[b,c,p]
// CHANGE vs r0: QSPLIT=4 blocks per (b,k) (1344 blocks vs 336), each owns a
// quarter of the p-range; wave shfl-reduce + 3 atomicAdds replaces the
// 9-barrier LDS tree. Atomic-order rounding ~1e-7 << 4.9e-4 tolerance.
__global__ __launch_bounds__(256) void k_q(const float* __restrict__ seg,
                                           const float* __restrict__ xd,
                                           float* __restrict__ q) {
    int bk   = blockIdx.x / QSPLIT;
    int part = blockIdx.x % QSPLIT;
    int b = bk / KN, k = bk % KN;
    const float* sg = seg + ((size_t)b * KN + k) * SP;
    const float* xb = xd + (size_t)b * 3 * SP;
    float a0 = 0.f, a1 = 0.f, a2 = 0.f;
    int p0 = part * (SP / QSPLIT);
    for (int p = p0 + threadIdx.x; p < p0 + SP / QSPLIT; p += 256) {
        float sv = sg[p];
        a0 = fmaf(sv, xb[p], a0);
        a1 = fmaf(sv, xb[SP + p], a1);
        a2 = fmaf(sv, xb[2 * SP + p], a2);
    }
    for (int off = 32; off > 0; off >>= 1) {
        a0 += __shfl_down(a0, off, 64);
        a1 += __shfl_down(a1, off, 64);
        a2 += __shfl_down(a2, off, 64);
    }
    __shared__ float red[4][3];
    int lane = threadIdx.x & 63, w = threadIdx.x >> 6;
    if (lane == 0) { red[w][0] = a0; red[w][1] = a1; red[w][2] = a2; }
    __syncthreads();
    if (threadIdx.x == 0) {
        const float scale = 1.0f / (float)BP;
        float s0 = red[0][0] + red[1][0] + red[2][0] + red[3][0];
        float s1 = red[0][1] + red[1][1] + red[2][1] + red[3][1];
        float s2 = red[0][2] + red[1][2] + red[2][2] + red[3][2];
        float* qo = q + ((size_t)b * KN + k) * 3;
        atomicAdd(qo + 0, s0 * scale);
        atomicAdd(qo + 1, s1 * scale);
        atomicAdd(qo + 2, s2 * scale);
    }
}

// ---------------------------------------------------------------------------
// attn[b,k,p] = sum_c x[b,c,p] * q[b,k,c]; float4, nontemporal stores
// (identical to r0 — untouched this round)
__global__ __launch_bounds__(256) void k_attn(const float* __restrict__ x,
                                              const float* __restrict__ q,
                                              float* __restrict__ out) {
    int b   = blockIdx.x >> 8;
    int blk = blockIdx.x & 255;
    int p4  = blk * 256 + threadIdx.x;

    const f32x4* xb = (const f32x4*)(x + (size_t)b * 3 * BP);
    f32x4 x0 = xb[p4];
    f32x4 x1 = xb[BP / 4 + p4];
    f32x4 x2 = xb[2 * (BP / 4) + p4];

    __shared__ float qs[KN * 3];
    if (threadIdx.x < KN * 3) qs[threadIdx.x] = q[(size_t)b * KN * 3 + threadIdx.x];
    __syncthreads();

    f32x4* ob = (f32x4*)(out + (size_t)b * KN * BP) + p4;
#pragma unroll
    for (int k = 0; k < KN; ++k) {
        float q0 = qs[k * 3], q1 = qs[k * 3 + 1], q2 = qs[k * 3 + 2];
        f32x4 r = x0 * q0 + x1 * q1 + x2 * q2;
        __builtin_nontemporal_store(r, ob + (size_t)k * (BP / 4));
    }
}

// ---------------------------------------------------------------------------
extern "C" void kernel_launch(void* const* d_in, const int* in_sizes, int n_in,
                              void* d_out, int out_size, void* d_ws, size_t ws_size,
                              hipStream_t stream) {
    const float* fm = (const float*)d_in[0];   // [16,256,64,64]
    const float* x  = (const float*)d_in[1];   // [16,3,512,512]
    const float* cw = (const float*)d_in[2];   // [21,256]
    const float* cb = (const float*)d_in[3];   // [21]
    float* out = (float*)d_out;                // [16,21,512,512]

    // workspace layout (floats): seg | tmpA | xd | q  (~12.6 MB total)
    float* seg  = (float*)d_ws;                       // 16*21*4096
    float* tmpA = seg  + (size_t)BN * KN * SP;        // 16*3*512*64
    float* xd   = tmpA + (size_t)BN * 3 * BH * SW;    // 16*3*4096
    float* q    = xd   + (size_t)BN * 3 * SP;         // 16*21*3

    k_phase1<<<SEG_BLOCKS + DOWNX_BLOCKS, 256, 0, stream>>>(fm, cw, cb, x, seg, tmpA);
    k_downy <<<BN * 3 * SP / 256,         256, 0, stream>>>(tmpA, xd, q);
    k_q     <<<BN * KN * QSPLIT,          256, 0, stream>>>(seg, xd, q);
    k_attn  <<<BN * (BP / 1024),          256, 0, stream>>>(x, q, out);
}

// Round 4
// 478.829 us; speedup vs baseline: 1.1800x; 1.0025x over previous
//
#include <hip/hip_runtime.h>

// Problem dims (fixed by setup_inputs)
#define BN 16      // batch
#define FD 256     // features
#define SH 64      // small h
#define SW 64      // small w
#define BH 512     // big H
#define BW 512     // big W
#define KN 21      // classes
#define SP (SH*SW)   // 4096 small pixels
#define BP (BH*BW)   // 262144 big pixels

#define SEG_BLOCKS 256                 // 65536 threads, 1 px each
#define DOWNX_BLOCKS (BN*3*BH/4)       // 6144: one block = (bc, 4 Y rows)
#define QSPLIT 4                       // k_q parallelism: 4 blocks per (b,k)

typedef float f32x4 __attribute__((ext_vector_type(4)));

// ---------------------------------------------------------------------------
// Adjoint bilinear (align_corners=True) weight, f32.
// CHANGE vs r3: f64 -> f32 (verified correct in r1, identical absmax).
// Exactness: X*63/511 is integral only at X=73m (t=9m, exact in f32);
// elsewhere min distance to an integer is 1/511 ~ 2e-3 >> f32 error ~4e-6,
// so floor() never crosses; residual weight error ~3e-8 << 4.9e-4 tolerance.
// Why it matters: f64 mul/cvt run at half rate and the old version spent
// more VALU on weights than on data FMAs in the 17-iteration inner loops.
__device__ __forceinline__ float adj_w(int big, int small) {
    float t = (float)big * (63.0f / 511.0f);
    int i0 = (int)t;
    float fr = t - (float)i0;
    int i1 = i0 + 1; if (i1 > 63) i1 = 63;
    float w = 0.0f;
    if (i0 == small) w += 1.0f - fr;
    if (i1 == small) w += fr;
    return w;
}

__device__ __forceinline__ void adj_range(int small, int& lo, int& hi) {
    lo = (int)floorf((small - 1) * (511.0f / 63.0f)); if (lo < 0) lo = 0;
    hi = (int)ceilf((small + 1) * (511.0f / 63.0f));  if (hi > 511) hi = 511;
}

// ---------------------------------------------------------------------------
// seg: 1x1 conv + softmax, ONE pixel per thread (identical to r3).
__device__ __forceinline__ void seg_body(int blk, int tid,
                                         const float* __restrict__ fm,
                                         const float* __restrict__ cw,
                                         const float* __restrict__ cb,
                                         float* __restrict__ seg) {
    int gid = blk * 256 + tid;          // 0..65535
    int b   = gid >> 12;                // 4096 px per batch
    int p   = gid & 4095;
    const float* fmb = fm + (size_t)b * FD * SP + p;

    float acc[KN];
#pragma unroll
    for (int k = 0; k < KN; ++k) acc[k] = 0.0f;

#pragma unroll 4
    for (int f = 0; f < FD; ++f) {
        float v = fmb[(size_t)f * SP];   // 256B coalesced per wave
#pragma unroll
        for (int k = 0; k < KN; ++k)
            acc[k] = fmaf(v, cw[k * FD + f], acc[k]);   // cw uniform -> s_load
    }

    float mx = -1e30f;
#pragma unroll
    for (int k = 0; k < KN; ++k) { acc[k] += cb[k]; mx = fmaxf(mx, acc[k]); }
    float s = 0.0f;
#pragma unroll
    for (int k = 0; k < KN; ++k) { acc[k] = expf(acc[k] - mx); s += acc[k]; }
    float inv = 1.0f / s;

    float* segb = seg + (size_t)b * KN * SP + p;
#pragma unroll
    for (int k = 0; k < KN; ++k) segb[(size_t)k * SP] = acc[k] * inv;   // 256B coalesced
}

// downx: tmpA[bc, Y, s] = sum_X W[X,s] * x[bc, Y, X]
// CHANGE vs r3 (isolated from r1's bundle): LDS-staged. Old version: each
// lane issued 17 scalar gathers spanning 2KB/wave = ~544 cache-line
// transactions per wave per row (L1-serialized). New: block loads 4 full
// rows (8 KB) with 512 coalesced float4 loads, then gathers from LDS.
__device__ __forceinline__ void downx_body(int blk, int tid,
                                           const float* __restrict__ x,
                                           float* __restrict__ tmpA,
                                           float (*rows)[BW]) {
    int bc = blk >> 7;                  // 0..47
    int Y0 = (blk & 127) << 2;          // 4 Y rows per block
    const f32x4* src = (const f32x4*)(x + ((size_t)bc * BH + Y0) * BW);
    f32x4* dst = (f32x4*)&rows[0][0];
    dst[tid]       = src[tid];          // 2048 floats = 512 float4, 2/thread
    dst[tid + 256] = src[tid + 256];
    __syncthreads();

    int s  = tid & 63;
    int yl = tid >> 6;
    int lo, hi; adj_range(s, lo, hi);
    float acc = 0.0f;
    for (int X = lo; X <= hi; ++X) acc = fmaf(adj_w(X, s), rows[yl][X], acc);
    tmpA[((size_t)bc * BH + Y0 + yl) * SW + s] = acc;   // 256B coalesced
}

// Phase 1: seg (blocks [0,256)) runs concurrently with downx (blocks [256,6400))
__global__ __launch_bounds__(256) void k_phase1(const float* __restrict__ fm,
                                                const float* __restrict__ cw,
                                                const float* __restrict__ cb,
                                                const float* __restrict__ x,
                                                float* __restrict__ seg,
                                                float* __restrict__ tmpA) {
    __shared__ float rows[4][BW];       // 8 KB (unused by seg blocks)
    if (blockIdx.x < SEG_BLOCKS) seg_body(blockIdx.x, threadIdx.x, fm, cw, cb, seg);
    else                         downx_body(blockIdx.x - SEG_BLOCKS, threadIdx.x, x, tmpA, rows);
}

// ---------------------------------------------------------------------------
// downy: xd[bc, r, s] = sum_Y W[Y,r] * tmpA[bc, Y, s]  (r3 structure, f32 W;
// first 4 blocks zero q for k_q's atomic accumulation — kernel boundary
// orders the zeroing before k_q).
__global__ __launch_bounds__(256) void k_downy(const float* __restrict__ tmpA,
                                               float* __restrict__ xd,
                                               float* __restrict__ q) {
    if (blockIdx.x < 4) {
        int i = blockIdx.x * 256 + threadIdx.x;
        if (i < BN * KN * 3) q[i] = 0.0f;
    }
    int gid = blockIdx.x * 256 + threadIdx.x;   // ((bc)*SH + r)*SW + s
    int s  = gid & 63;
    int r  = (gid >> 6) & 63;
    int bc = gid >> 12;                          // 0..47
    const float* base = tmpA + (size_t)bc * BH * SW + s;
    int lo, hi; adj_range(r, lo, hi);
    float acc = 0.0f;
    for (int Y = lo; Y <= hi; ++Y) acc = fmaf(adj_w(Y, r), base[(size_t)Y * SW], acc);
    xd[gid] = acc;
}

// ---------------------------------------------------------------------------
// q[b,k,c] = (1/BP) * sum_p seg[b,k,p] * xd[b,c,p]   (identical to r3)
__global__ __launch_bounds__(256) void k_q(const float* __restrict__ seg,
                                           const float* __restrict__ xd,
                                           float* __restrict__ q) {
    int bk   = blockIdx.x / QSPLIT;
    int part = blockIdx.x % QSPLIT;
    int b = bk / KN, k = bk % KN;
    const float* sg = seg + ((size_t)b * KN + k) * SP;
    const float* xb = xd + (size_t)b * 3 * SP;
    float a0 = 0.f, a1 = 0.f, a2 = 0.f;
    int p0 = part * (SP / QSPLIT);
    for (int p = p0 + threadIdx.x; p < p0 + SP / QSPLIT; p += 256) {
        float sv = sg[p];
        a0 = fmaf(sv, xb[p], a0);
        a1 = fmaf(sv, xb[SP + p], a1);
        a2 = fmaf(sv, xb[2 * SP + p], a2);
    }
    for (int off = 32; off > 0; off >>= 1) {
        a0 += __shfl_down(a0, off, 64);
        a1 += __shfl_down(a1, off, 64);
        a2 += __shfl_down(a2, off, 64);
    }
    __shared__ float red[4][3];
    int lane = threadIdx.x & 63, w = threadIdx.x >> 6;
    if (lane == 0) { red[w][0] = a0; red[w][1] = a1; red[w][2] = a2; }
    __syncthreads();
    if (threadIdx.x == 0) {
        const float scale = 1.0f / (float)BP;
        float s0 = red[0][0] + red[1][0] + red[2][0] + red[3][0];
        float s1 = red[0][1] + red[1][1] + red[2][1] + red[3][1];
        float s2 = red[0][2] + red[1][2] + red[2][2] + red[3][2];
        float* qo = q + ((size_t)b * KN + k) * 3;
        atomicAdd(qo + 0, s0 * scale);
        atomicAdd(qo + 1, s1 * scale);
        atomicAdd(qo + 2, s2 * scale);
    }
}

// ---------------------------------------------------------------------------
// attn[b,k,p] = sum_c x[b,c,p] * q[b,k,c]; float4, nontemporal stores
// (identical to r0/r3 — NT stores kept; r1 evidence suggests regular
// stores were part of its regression)
__global__ __launch_bounds__(256) void k_attn(const float* __restrict__ x,
                                              const float* __restrict__ q,
                                              float* __restrict__ out) {
    int b   = blockIdx.x >> 8;
    int blk = blockIdx.x & 255;
    int p4  = blk * 256 + threadIdx.x;

    const f32x4* xb = (const f32x4*)(x + (size_t)b * 3 * BP);
    f32x4 x0 = xb[p4];
    f32x4 x1 = xb[BP / 4 + p4];
    f32x4 x2 = xb[2 * (BP / 4) + p4];

    __shared__ float qs[KN * 3];
    if (threadIdx.x < KN * 3) qs[threadIdx.x] = q[(size_t)b * KN * 3 + threadIdx.x];
    __syncthreads();

    f32x4* ob = (f32x4*)(out + (size_t)b * KN * BP) + p4;
#pragma unroll
    for (int k = 0; k < KN; ++k) {
        float q0 = qs[k * 3], q1 = qs[k * 3 + 1], q2 = qs[k * 3 + 2];
        f32x4 r = x0 * q0 + x1 * q1 + x2 * q2;
        __builtin_nontemporal_store(r, ob + (size_t)k * (BP / 4));
    }
}

// ---------------------------------------------------------------------------
extern "C" void kernel_launch(void* const* d_in, const int* in_sizes, int n_in,
                              void* d_out, int out_size, void* d_ws, size_t ws_size,
                              hipStream_t stream) {
    const float* fm = (const float*)d_in[0];   // [16,256,64,64]
    const float* x  = (const float*)d_in[1];   // [16,3,512,512]
    const float* cw = (const float*)d_in[2];   // [21,256]
    const float* cb = (const float*)d_in[3];   // [21]
    float* out = (float*)d_out;                // [16,21,512,512]

    // workspace layout (floats): seg | tmpA | xd | q  (~12.6 MB total)
    float* seg  = (float*)d_ws;                       // 16*21*4096
    float* tmpA = seg  + (size_t)BN * KN * SP;        // 16*3*512*64
    float* xd   = tmpA + (size_t)BN * 3 * BH * SW;    // 16*3*4096
    float* q    = xd   + (size_t)BN * 3 * SP;         // 16*21*3

    k_phase1<<<SEG_BLOCKS + DOWNX_BLOCKS, 256, 0, stream>>>(fm, cw, cb, x, seg, tmpA);
    k_downy <<<BN * 3 * SP / 256,         256, 0, stream>>>(tmpA, xd, q);
    k_q     <<<BN * KN * QSPLIT,          256, 0, stream>>>(seg, xd, q);
    k_attn  <<<BN * (BP / 1024),          256, 0, stream>>>(x, q, out);
}